// Round 4
// baseline (43.477 us; speedup 1.0000x reference)
//
#include <hip/hip_runtime.h>

#define BATCH 8
#define NUM_GENES 20000
#define FEAT 64

// Pass 1: find segment start offsets from sorted segment_ids.
__global__ __launch_bounds__(256)
void find_starts_kernel(const int* __restrict__ segment_ids,
                        int* __restrict__ starts, int total)
{
    int i = blockIdx.x * 256 + threadIdx.x;
    if (i < total) {
        int s = segment_ids[i];
        if (i == 0 || segment_ids[i - 1] != s) starts[s] = i;
    }
}

// Pass 2: 256-thread blocks = 4 waves; wave w handles segment group*4+w,
// all for the SAME batch b = bid & 7 so each batch plane (5.12 MB) stays
// pinned to one XCD's L2 (verified R2: FETCH 157->70 MB).
// Within a wave: lane = sub*16 + fq; sub picks one of 4 gene rows per
// iteration, fq picks the float4 feature quad. Indices are staged in 2
// registers/lane and broadcast via __shfl (register-only).
__global__ __launch_bounds__(256)
void genesets_pool_kernel(const float* __restrict__ gene,        // [B][G][F]
                          const int*   __restrict__ flat_indices,// [total]
                          const int*   __restrict__ starts,      // [S]
                          const int*   __restrict__ counts,      // [S]
                          float*       __restrict__ out,         // [B][S][F]
                          int num_segments)
{
    const int bid  = blockIdx.x;
    const int b    = bid & 7;                      // batch -> XCD
    const int wave = threadIdx.x >> 6;
    const int s    = (bid >> 3) * 4 + wave;        // segment
    const int lane = threadIdx.x & 63;
    const int sub  = lane >> 4;                    // 0..3
    const int fq   = lane & 15;                    // feature quad

    if (s >= num_segments) return;

    const int start = starts[s];
    const int cnt   = counts[s];

    // Stage all indices of this segment in registers (cnt < 128).
    int idx_a = (lane      < cnt) ? flat_indices[start + lane]      : 0;
    int idx_b = (lane + 64 < cnt) ? flat_indices[start + lane + 64] : 0;

    const float* gbase = gene + (size_t)b * NUM_GENES * FEAT + fq * 4;

    float4 acc = make_float4(0.f, 0.f, 0.f, 0.f);

    const int q  = cnt >> 2;          // full quads of 4 rows
    const int qa = (q < 16) ? q : 16; // quads served by idx_a (j < 64)

    #pragma unroll 4
    for (int k = 0; k < qa; ++k) {
        const int g = __shfl(idx_a, sub + 4 * k);
        const float4 v = *reinterpret_cast<const float4*>(gbase + (size_t)g * FEAT);
        acc.x += v.x; acc.y += v.y; acc.z += v.z; acc.w += v.w;
    }
    #pragma unroll 2
    for (int k = 16; k < q; ++k) {
        const int g = __shfl(idx_b, sub + 4 * k - 64);
        const float4 v = *reinterpret_cast<const float4*>(gbase + (size_t)g * FEAT);
        acc.x += v.x; acc.y += v.y; acc.z += v.z; acc.w += v.w;
    }
    // Tail: remaining cnt & 3 rows. Shfl executed uniformly; load predicated.
    {
        const int j = q * 4 + sub;                 // may exceed cnt
        const int g = (j < 64) ? __shfl(idx_a, j & 63) : __shfl(idx_b, j - 64);
        if (j < cnt) {
            const float4 v = *reinterpret_cast<const float4*>(gbase + (size_t)g * FEAT);
            acc.x += v.x; acc.y += v.y; acc.z += v.z; acc.w += v.w;
        }
    }

    // Reduce over the 4 sub-groups (lanes differing in bits 4..5).
    acc.x += __shfl_xor(acc.x, 16); acc.y += __shfl_xor(acc.y, 16);
    acc.z += __shfl_xor(acc.z, 16); acc.w += __shfl_xor(acc.w, 16);
    acc.x += __shfl_xor(acc.x, 32); acc.y += __shfl_xor(acc.y, 32);
    acc.z += __shfl_xor(acc.z, 32); acc.w += __shfl_xor(acc.w, 32);

    if (sub == 0) {
        const float inv = 1.0f / (float)cnt;
        float4 r = make_float4(acc.x * inv, acc.y * inv, acc.z * inv, acc.w * inv);
        *reinterpret_cast<float4*>(out + ((size_t)b * num_segments + s) * FEAT + fq * 4) = r;
    }
}

extern "C" void kernel_launch(void* const* d_in, const int* in_sizes, int n_in,
                              void* d_out, int out_size, void* d_ws, size_t ws_size,
                              hipStream_t stream)
{
    const float* gene         = (const float*)d_in[0];
    const int*   flat_indices = (const int*)d_in[1];
    const int*   segment_ids  = (const int*)d_in[2];
    const int*   counts       = (const int*)d_in[3];
    float*       out          = (float*)d_out;

    const int total        = in_sizes[1];
    const int num_segments = in_sizes[3];

    int* starts = (int*)d_ws;          // num_segments ints of scratch

    find_starts_kernel<<<(total + 255) / 256, 256, 0, stream>>>(segment_ids, starts, total);

    const int seg_groups = (num_segments + 3) / 4;
    const int nblocks    = seg_groups * BATCH;
    genesets_pool_kernel<<<nblocks, 256, 0, stream>>>(gene, flat_indices, starts,
                                                      counts, out, num_segments);
}

// Round 5
// 32.566 us; speedup vs baseline: 1.3351x; 1.3351x over previous
//
#include <hip/hip_runtime.h>

#define BATCH 8
#define NUM_GENES 20000
#define FEAT 64

// Pass 1: find segment start offsets from sorted segment_ids.
__global__ __launch_bounds__(256)
void find_starts_kernel(const int* __restrict__ segment_ids,
                        int* __restrict__ starts, int total)
{
    int i = blockIdx.x * 256 + threadIdx.x;
    if (i < total) {
        int s = segment_ids[i];
        if (i == 0 || segment_ids[i - 1] != s) starts[s] = i;
    }
}

// Pass 2: 256-thread blocks = 4 waves; wave w handles segment group*4+w,
// all for the SAME batch b = bid & 7 (XCD pinning: verified R2, FETCH
// 157->70 MB). lane = sub*16 + fq; sub picks one of 4 gene rows per
// gather instruction, fq the float4 feature quad.
//
// Gather loop is software-pipelined in chunks of 8: all 8 predicated
// loads of a chunk are issued into registers (static indices, fully
// unrolled) before any accumulation -> ~8-deep vmcnt window per wave.
__global__ __launch_bounds__(256)
void genesets_pool_kernel(const float* __restrict__ gene,        // [B][G][F]
                          const int*   __restrict__ flat_indices,// [total]
                          const int*   __restrict__ starts,      // [S]
                          const int*   __restrict__ counts,      // [S]
                          float*       __restrict__ out,         // [B][S][F]
                          int num_segments)
{
    const int bid  = blockIdx.x;
    const int b    = bid & 7;                      // batch -> XCD
    const int wave = threadIdx.x >> 6;
    const int s    = (bid >> 3) * 4 + wave;        // segment
    const int lane = threadIdx.x & 63;
    const int sub  = lane >> 4;                    // 0..3
    const int fq   = lane & 15;                    // feature quad

    if (s >= num_segments) return;

    const int start = starts[s];
    const int cnt   = counts[s];

    // Stage all indices of this segment in registers (cnt < 128).
    int idx_a = (lane      < cnt) ? flat_indices[start + lane]      : 0;
    int idx_b = (lane + 64 < cnt) ? flat_indices[start + lane + 64] : 0;

    const float* gbase = gene + (size_t)b * NUM_GENES * FEAT + fq * 4;

    float4 acc = make_float4(0.f, 0.f, 0.f, 0.f);
    const int kn = (cnt + 3) >> 2;     // quads (uniform per wave), <= 23

    for (int c = 0; c < kn; c += 8) {
        float4 buf[8];
        #pragma unroll
        for (int p = 0; p < 8; ++p) {
            const int k = c + p;
            const int j = sub + 4 * k;
            const int g = (j < 64) ? __shfl(idx_a, j) : __shfl(idx_b, j & 63);
            if (k < kn && j < cnt) {
                buf[p] = *reinterpret_cast<const float4*>(gbase + (size_t)g * FEAT);
            } else {
                buf[p] = make_float4(0.f, 0.f, 0.f, 0.f);
            }
        }
        #pragma unroll
        for (int p = 0; p < 8; ++p) {
            acc.x += buf[p].x; acc.y += buf[p].y;
            acc.z += buf[p].z; acc.w += buf[p].w;
        }
    }

    // Reduce over the 4 sub-groups (lanes differing in bits 4..5).
    acc.x += __shfl_xor(acc.x, 16); acc.y += __shfl_xor(acc.y, 16);
    acc.z += __shfl_xor(acc.z, 16); acc.w += __shfl_xor(acc.w, 16);
    acc.x += __shfl_xor(acc.x, 32); acc.y += __shfl_xor(acc.y, 32);
    acc.z += __shfl_xor(acc.z, 32); acc.w += __shfl_xor(acc.w, 32);

    if (sub == 0) {
        const float inv = 1.0f / (float)cnt;
        float4 r = make_float4(acc.x * inv, acc.y * inv, acc.z * inv, acc.w * inv);
        *reinterpret_cast<float4*>(out + ((size_t)b * num_segments + s) * FEAT + fq * 4) = r;
    }
}

extern "C" void kernel_launch(void* const* d_in, const int* in_sizes, int n_in,
                              void* d_out, int out_size, void* d_ws, size_t ws_size,
                              hipStream_t stream)
{
    const float* gene         = (const float*)d_in[0];
    const int*   flat_indices = (const int*)d_in[1];
    const int*   segment_ids  = (const int*)d_in[2];
    const int*   counts       = (const int*)d_in[3];
    float*       out          = (float*)d_out;

    const int total        = in_sizes[1];
    const int num_segments = in_sizes[3];

    int* starts = (int*)d_ws;          // num_segments ints of scratch

    find_starts_kernel<<<(total + 255) / 256, 256, 0, stream>>>(segment_ids, starts, total);

    const int seg_groups = (num_segments + 3) / 4;
    const int nblocks    = seg_groups * BATCH;
    genesets_pool_kernel<<<nblocks, 256, 0, stream>>>(gene, flat_indices, starts,
                                                      counts, out, num_segments);
}